// Round 18
// baseline (182.193 us; speedup 1.0000x reference)
//
#include <hip/hip_runtime.h>
#include <hip/hip_fp16.h>

typedef _Float16 f16x8 __attribute__((ext_vector_type(8)));
typedef _Float16 f16x4 __attribute__((ext_vector_type(4)));
typedef float f32x16 __attribute__((ext_vector_type(16)));
typedef float f32x4 __attribute__((ext_vector_type(4)));

#define LOG2E 1.44269504088896340736f
#define QSCALE 0.18033688011112042f      /* 0.125 * log2(e), folded into Q */
#define MASKC 1.8033688e8f               /* 1e9 * 0.125 * log2(e) */

typedef __attribute__((address_space(1))) const unsigned char gl_byte;
typedef __attribute__((address_space(3))) unsigned char lds_byte;

#define GLOAD_LDS16(g, l) \
  __builtin_amdgcn_global_load_lds((const gl_byte*)(g), (lds_byte*)(l), 16, 0, 0)

static __device__ __forceinline__ f32x16 zero16() {
  f32x16 z;
#pragma unroll
  for (int i = 0; i < 16; ++i) z[i] = 0.0f;
  return z;
}

static __device__ __forceinline__ unsigned pkh(float a, float b) {
  union { _Float16 h[2]; unsigned u; } t;
  t.h[0] = (_Float16)a; t.h[1] = (_Float16)b;
  return t.u;
}

// exchange: a = (hi ? partner's y : own x), c = (hi ? own y : partner's x)
static __device__ __forceinline__ void swap32(unsigned x, unsigned y, int hi,
                                              unsigned& a, unsigned& c) {
  unsigned py = (unsigned)__shfl_xor((int)y, 32);
  unsigned px = (unsigned)__shfl_xor((int)x, 32);
  a = hi ? py : x;
  c = hi ? y : px;
}

// XCD-aware bijective remap for 1024-block grids (16,16,4).
static __device__ __forceinline__ void xcd_remap_1k(int& q0, int& bh, int& z) {
  int lin = blockIdx.x + (blockIdx.y << 4) + (blockIdx.z << 8);
  int wid = ((lin & 7) << 7) | (lin >> 3);
  q0 = (wid & 15) * 128;
  bh = (wid >> 4) & 15;
  z = wid >> 8;
}

// 256-thread stage of one 64x64-half K tile (8KB): 2 DMA issues per thread
static __device__ __forceinline__ void stage_k64_256(char* dst,
                                                     const _Float16* __restrict__ kr,
                                                     int b, int h, int kb, int tid) {
#pragma unroll
  for (int it = 0; it < 2; ++it) {
    int s = it * 256 + tid;
    int r = s >> 3, c8 = (s & 7) ^ (r & 7);
    const _Float16* g = kr + (size_t)(b * 2048 + kb * 64 + r) * 512 + h * 64 + c8 * 8;
    GLOAD_LDS16(g, dst + (it * 256 + (tid & 192)) * 16);
  }
}

// ---------------------------------------------------------------------------
// Fused projections + mask scan.
// z=0 -> rope(q@Wq^T)*QSCALE, z=1 -> rope(k@Wk^T), z=2 -> v_t, z=3 -> mask.
// Tile 64(M) x 128(N), BK=64, 256 threads (4 waves, 2x2). grid (4, 64, 4).
// ---------------------------------------------------------------------------
__global__ __launch_bounds__(256) void proj_kernel(
    const float* __restrict__ qin, const float* __restrict__ kin,
    const float* __restrict__ vin, const float* __restrict__ Wq,
    const float* __restrict__ Wk, const float* __restrict__ Wv,
    const float* __restrict__ mask, int* __restrict__ flag,
    _Float16* __restrict__ q_r, _Float16* __restrict__ k_r,
    _Float16* __restrict__ v_t) {
  __shared__ char smem[8192 + 16384];  // As [64][64] f16, Ws [128][64] f16
  const int tid = threadIdx.x;
  const int zz = blockIdx.z;

  if (zz == 3) {  // mask scan: 256 blocks x 256 thr x 32 float4 = 64 MB
    int bid = blockIdx.y * 4 + blockIdx.x;
    const float4* m4p = (const float4*)mask;
    int base = bid * 8192 + tid;
    bool nz = false;
#pragma unroll 4
    for (int i = 0; i < 32; ++i) {
      float4 v = m4p[base + i * 256];
      nz |= (v.x != 0.f) || (v.y != 0.f) || (v.z != 0.f) || (v.w != 0.f);
    }
    if (__any(nz) && (tid & 63) == 0) atomicOr(flag, 1);
    return;
  }

  const int l = tid & 63, lo = l & 31, hi = l >> 5;
  const int w = tid >> 6, wm = w >> 1, wn = w & 1;
  const int m0 = blockIdx.y * 64, n0 = blockIdx.x * 128;
  const float* A = zz == 0 ? qin : zz == 1 ? kin : vin;
  const float* W = zz == 0 ? Wq : zz == 1 ? Wk : Wv;

  f32x16 acc[2];
  acc[0] = zero16();
  acc[1] = zero16();

  for (int kb = 0; kb < 8; ++kb) {
#pragma unroll
    for (int i = 0; i < 4; ++i) {
      int idx = tid + 256 * i; int r = idx >> 4, c4 = idx & 15;
      float4 v = *(const float4*)(A + (size_t)(m0 + r) * 512 + kb * 64 + c4 * 4);
      uint2 uu; uu.x = pkh(v.x, v.y); uu.y = pkh(v.z, v.w);
      *(uint2*)(smem + ((r * 128 + c4 * 8) ^ ((r & 7) << 4))) = uu;
    }
#pragma unroll
    for (int i = 0; i < 8; ++i) {
      int idx = tid + 256 * i; int r = idx >> 4, c4 = idx & 15;
      float4 v = *(const float4*)(W + (size_t)(n0 + r) * 512 + kb * 64 + c4 * 4);
      uint2 uu; uu.x = pkh(v.x, v.y); uu.y = pkh(v.z, v.w);
      *(uint2*)(smem + 8192 + ((r * 128 + c4 * 8) ^ ((r & 7) << 4))) = uu;
    }
    __syncthreads();
#pragma unroll
    for (int ks = 0; ks < 4; ++ks) {
      int ra = wm * 32 + lo;
      f16x8 a0 = *(const f16x8*)(smem + ((ra * 128 + ks * 32 + hi * 16) ^ ((ra & 7) << 4)));
      int rb0 = wn * 64 + lo, rb1 = rb0 + 32;
      f16x8 b0 = *(const f16x8*)(smem + 8192 + ((rb0 * 128 + ks * 32 + hi * 16) ^ ((rb0 & 7) << 4)));
      f16x8 b1 = *(const f16x8*)(smem + 8192 + ((rb1 * 128 + ks * 32 + hi * 16) ^ ((rb1 & 7) << 4)));
      acc[0] = __builtin_amdgcn_mfma_f32_32x32x16_f16(a0, b0, acc[0], 0, 0, 0);
      acc[1] = __builtin_amdgcn_mfma_f32_32x32x16_f16(a0, b1, acc[1], 0, 0, 0);
    }
    __syncthreads();
  }

  if (zz < 2) {
    _Float16* out = zz ? k_r : q_r;
#pragma unroll
    for (int nt = 0; nt < 2; ++nt) {
      int n = n0 + wn * 64 + nt * 32 + lo;
      int odd = lo & 1;
      int ii = (n >> 1) & 255;
      float fr = exp2f(-(float)ii * 0.05190512648261504f);
#pragma unroll
      for (int r = 0; r < 16; ++r) {
        int m = m0 + wm * 32 + (r & 3) + 8 * ((r >> 2) & 3) + 4 * hi;
        float a = acc[nt][r];
        float bb = __shfl_xor(a, 1);
        float xe = odd ? bb : a, xo = odd ? a : bb;
        float ang = (float)(m & 2047) * fr;
        float sn, cs;
        sincosf(ang, &sn, &cs);
        float res = odd ? (xo * cs + xe * sn) : (xe * cs - xo * sn);
        if (zz == 0) res *= QSCALE;  // fold softmax scale into Q
        out[(size_t)m * 512 + ii + (odd ? 256 : 0)] = (_Float16)res;
      }
    }
  } else {
#pragma unroll
    for (int nt = 0; nt < 2; ++nt) {
      int n = n0 + wn * 64 + nt * 32 + lo;
      int hh = n >> 6, d = n & 63;
#pragma unroll
      for (int a = 0; a < 4; ++a) {
        int m = m0 + wm * 32 + 8 * a + 4 * hi;
        int b_ = m >> 11, s = m & 2047;
        uint2 uu;
        uu.x = pkh(acc[nt][4 * a + 0], acc[nt][4 * a + 1]);
        uu.y = pkh(acc[nt][4 * a + 2], acc[nt][4 * a + 3]);
        *(uint2*)(v_t + (size_t)((b_ * 8 + hh) * 64 + d) * 2048 + s) = uu;
      }
    }
  }
}

// ---------------------------------------------------------------------------
// Output GEMM: d_out = (sum of 4 f16 PV partial slabs) @ Wo^T, f32 out.
// ---------------------------------------------------------------------------
__global__ __launch_bounds__(256) void out_gemm(const _Float16* __restrict__ opart,
                                                const float* __restrict__ W,
                                                float* __restrict__ out) {
  __shared__ char smem[8192 + 16384];
  const int tid = threadIdx.x;
  const int l = tid & 63, lo = l & 31, hi = l >> 5;
  const int w = tid >> 6, wm = w >> 1, wn = w & 1;
  const int m0 = blockIdx.y * 64, n0 = blockIdx.x * 128;
  const size_t slab = (size_t)4096 * 512;

  f32x16 acc[2];
  acc[0] = zero16();
  acc[1] = zero16();

  for (int kb = 0; kb < 8; ++kb) {
#pragma unroll
    for (int i = 0; i < 4; ++i) {
      int idx = tid + 256 * i; int r = idx >> 4, c4 = idx & 15;
      size_t off = (size_t)(m0 + r) * 512 + kb * 64 + c4 * 4;
      f16x4 x = *(const f16x4*)(opart + off);
      f16x4 y = *(const f16x4*)(opart + slab + off);
      f16x4 u = *(const f16x4*)(opart + 2 * slab + off);
      f16x4 t = *(const f16x4*)(opart + 3 * slab + off);
      float s0 = (float)x[0] + (float)y[0] + (float)u[0] + (float)t[0];
      float s1 = (float)x[1] + (float)y[1] + (float)u[1] + (float)t[1];
      float s2 = (float)x[2] + (float)y[2] + (float)u[2] + (float)t[2];
      float s3 = (float)x[3] + (float)y[3] + (float)u[3] + (float)t[3];
      uint2 uu; uu.x = pkh(s0, s1); uu.y = pkh(s2, s3);
      *(uint2*)(smem + ((r * 128 + c4 * 8) ^ ((r & 7) << 4))) = uu;
    }
#pragma unroll
    for (int i = 0; i < 8; ++i) {
      int idx = tid + 256 * i; int r = idx >> 4, c4 = idx & 15;
      float4 v = *(const float4*)(W + (size_t)(n0 + r) * 512 + kb * 64 + c4 * 4);
      uint2 uu; uu.x = pkh(v.x, v.y); uu.y = pkh(v.z, v.w);
      *(uint2*)(smem + 8192 + ((r * 128 + c4 * 8) ^ ((r & 7) << 4))) = uu;
    }
    __syncthreads();
#pragma unroll
    for (int ks = 0; ks < 4; ++ks) {
      int ra = wm * 32 + lo;
      f16x8 a0 = *(const f16x8*)(smem + ((ra * 128 + ks * 32 + hi * 16) ^ ((ra & 7) << 4)));
      int rb0 = wn * 64 + lo, rb1 = rb0 + 32;
      f16x8 b0 = *(const f16x8*)(smem + 8192 + ((rb0 * 128 + ks * 32 + hi * 16) ^ ((rb0 & 7) << 4)));
      f16x8 b1 = *(const f16x8*)(smem + 8192 + ((rb1 * 128 + ks * 32 + hi * 16) ^ ((rb1 & 7) << 4)));
      acc[0] = __builtin_amdgcn_mfma_f32_32x32x16_f16(a0, b0, acc[0], 0, 0, 0);
      acc[1] = __builtin_amdgcn_mfma_f32_32x32x16_f16(a0, b1, acc[1], 0, 0, 0);
    }
    __syncthreads();
  }

#pragma unroll
  for (int nt = 0; nt < 2; ++nt) {
    int n = n0 + wn * 64 + nt * 32 + lo;
#pragma unroll
    for (int r = 0; r < 16; ++r) {
      int m = m0 + wm * 32 + (r & 3) + 8 * ((r >> 2) & 3) + 4 * hi;
      out[(size_t)m * 512 + n] = acc[nt][r];
    }
  }
}

// ---------------------------------------------------------------------------
// Pass 1: softmax denominators, k-split 4.  grid (16 qt, 16 bh, 4 z), 256 thr
// (4 waves, q-tile 128).  LDS 16KB: K double-buffer 2x8KB.
// s_setprio(1) around the QK MFMA cluster (T5).
// ---------------------------------------------------------------------------
__global__ __launch_bounds__(256, 4) void lsum_kernel(
    const _Float16* __restrict__ qr, const _Float16* __restrict__ kr,
    const float* __restrict__ mask, const int* __restrict__ flagp,
    float* __restrict__ lsums) {
  __shared__ char smem[16384];
  const int tid = threadIdx.x;
  const int w = tid >> 6, l = tid & 63, lo = l & 31, hi = l >> 5;
  int q0, bh, z;
  xcd_remap_1k(q0, bh, z);
  const int b = bh >> 3, h = bh & 7;
  const int mflag = *flagp;
  const int qw = q0 + w * 32 + lo;

  // Q B-fragments direct from global
  f16x8 qf[4];
  {
    const _Float16* qrow = qr + (size_t)(b * 2048 + qw) * 512 + h * 64 + hi * 8;
#pragma unroll
    for (int ks = 0; ks < 4; ++ks) qf[ks] = *(const f16x8*)(qrow + ks * 16);
  }

  const int kb0 = z * 8;
  stage_k64_256(smem, kr, b, h, kb0, tid);
  __syncthreads();

  float lsum = 0.f;
  for (int t = 0; t < 8; ++t) {
    const int cur = t & 1, kb = kb0 + t;
    if (t < 7) stage_k64_256(smem + (cur ^ 1) * 8192, kr, b, h, kb + 1, tid);
    char* kbuf = smem + cur * 8192;
#pragma unroll
    for (int ks4 = 0; ks4 < 2; ++ks4) {
      f32x16 acc = zero16();
      int krw = ks4 * 32 + lo;
      __builtin_amdgcn_s_setprio(1);
#pragma unroll
      for (int ks = 0; ks < 4; ++ks) {
        f16x8 kf = *(const f16x8*)(kbuf + ((krw * 128 + ks * 32 + hi * 16) ^ ((krw & 7) << 4)));
        acc = __builtin_amdgcn_mfma_f32_32x32x16_f16(kf, qf[ks], acc, 0, 0, 0);
      }
      __builtin_amdgcn_s_setprio(0);
      if (!mflag) {
#pragma unroll
        for (int r = 0; r < 16; ++r) lsum += exp2f(acc[r]);
      } else {
#pragma unroll
        for (int r = 0; r < 16; ++r) {
          int kg = kb * 64 + ks4 * 32 + (r & 3) + 8 * ((r >> 2) & 3) + 4 * hi;
          float mv = mask[(size_t)(b * 2048 + qw) * 2048 + kg];
          lsum += exp2f(acc[r] - MASKC * mv);
        }
      }
    }
    __syncthreads();
  }
  lsum += __shfl_xor(lsum, 32);
  if (hi == 0) lsums[(size_t)(z * 16 + bh) * 2048 + qw] = lsum;
}

// ---------------------------------------------------------------------------
// Pass 2: scores + partial PV, k-split 4.  grid (16 qt, 16 bh, 4 z), 256 thr
// (4 waves, q-tile 128).  LDS 32KB: K dbuf 2x8KB @0, per-wave transpose
// @16384.  s_setprio(1) around the QK and PV MFMA clusters (T5; resident
// waves are phase-staggered so the CU scheduler has something to arbitrate).
// ---------------------------------------------------------------------------
__global__ __launch_bounds__(256, 4) void attn_kernel(
    const _Float16* __restrict__ qr, const _Float16* __restrict__ kr,
    const _Float16* __restrict__ vt, const float* __restrict__ mask,
    const int* __restrict__ flagp, const float* __restrict__ lsums,
    float* __restrict__ scores, _Float16* __restrict__ opart) {
  __shared__ char smem[32768];
  const int tid = threadIdx.x;
  const int w = tid >> 6, l = tid & 63, lo = l & 31, hi = l >> 5;
  int q0, bh, z;
  xcd_remap_1k(q0, bh, z);
  const int b = bh >> 3, h = bh & 7;
  const int mflag = *flagp;
  const int qw = q0 + w * 32 + lo;

  f16x8 qf[4];
  {
    const _Float16* qrow = qr + (size_t)(b * 2048 + qw) * 512 + h * 64 + hi * 8;
#pragma unroll
    for (int ks = 0; ks < 4; ++ks) qf[ks] = *(const f16x8*)(qrow + ks * 16);
  }

  float lsum = 0.f;
#pragma unroll
  for (int zz = 0; zz < 4; ++zz) lsum += lsums[(size_t)(zz * 16 + bh) * 2048 + qw];
  const float linv = -log2f(lsum);  // fold 1/lsum into the exponent

  f32x16 oacc[2];
  oacc[0] = zero16();
  oacc[1] = zero16();
  char* trw = smem + 16384 + (w << 12);  // per-wave [32 q][8 groups x 16B]
  const _Float16* vbase = vt + (size_t)((b * 8 + h) * 64) * 2048;

  const int kb0 = z * 8;
  stage_k64_256(smem, kr, b, h, kb0, tid);
  __syncthreads();

  for (int t = 0; t < 8; ++t) {
    const int cur = t & 1, kb = kb0 + t;
    if (t < 7) stage_k64_256(smem + (cur ^ 1) * 8192, kr, b, h, kb + 1, tid);
    // prefetch V A-fragments for this tile (consumed after the S phase)
    f16x8 vp[8];
#pragma unroll
    for (int f = 0; f < 8; ++f) {
      int ks4 = f >> 2, kb2 = (f >> 1) & 1, dt = f & 1;
      int d = dt * 32 + lo;
      vp[f] = *(const f16x8*)(vbase + (size_t)d * 2048 + kb * 64 + ks4 * 32 + kb2 * 16 + hi * 8);
    }
    char* kbuf = smem + cur * 8192;
#pragma unroll
    for (int ks4 = 0; ks4 < 2; ++ks4) {
      f32x16 acc = zero16();
      int krw = ks4 * 32 + lo;
      __builtin_amdgcn_s_setprio(1);
#pragma unroll
      for (int ks = 0; ks < 4; ++ks) {
        f16x8 kf = *(const f16x8*)(kbuf + ((krw * 128 + ks * 32 + hi * 16) ^ ((krw & 7) << 4)));
        acc = __builtin_amdgcn_mfma_f32_32x32x16_f16(kf, qf[ks], acc, 0, 0, 0);
      }
      __builtin_amdgcn_s_setprio(0);
      float p[16];
      if (!mflag) {
#pragma unroll
        for (int r = 0; r < 16; ++r) p[r] = exp2f(acc[r] + linv);
      } else {
#pragma unroll
        for (int r = 0; r < 16; ++r) {
          int kg = kb * 64 + ks4 * 32 + (r & 3) + 8 * ((r >> 2) & 3) + 4 * hi;
          float mv = mask[(size_t)(b * 2048 + qw) * 2048 + kg];
          p[r] = exp2f(acc[r] - MASKC * mv + linv);
        }
      }
      // quad transpose writes: p[4a..4a+3] -> group (2a+hi)^(lo>>2) of row lo
#pragma unroll
      for (int a = 0; a < 4; ++a) {
        int g = ((2 * a + hi) ^ (lo >> 2)) & 7;
        f32x4 v;
        v[0] = p[4 * a + 0]; v[1] = p[4 * a + 1];
        v[2] = p[4 * a + 2]; v[3] = p[4 * a + 3];
        *(f32x4*)(trw + lo * 128 + (g << 4)) = v;
      }
      // PV: build P^T fragments in-register, A = prefetched V fragments
      __builtin_amdgcn_s_setprio(1);
#pragma unroll
      for (int kb2 = 0; kb2 < 2; ++kb2) {
        unsigned X0 = pkh(p[8 * kb2 + 0], p[8 * kb2 + 1]);
        unsigned X1 = pkh(p[8 * kb2 + 2], p[8 * kb2 + 3]);
        unsigned Y0 = pkh(p[8 * kb2 + 4], p[8 * kb2 + 5]);
        unsigned Y1 = pkh(p[8 * kb2 + 6], p[8 * kb2 + 7]);
        unsigned w0, w1, w2, w3;
        swap32(X0, Y0, hi, w0, w2);
        swap32(X1, Y1, hi, w1, w3);
        union { unsigned u[4]; f16x8 v; } pf;
        pf.u[0] = w0; pf.u[1] = w1; pf.u[2] = w2; pf.u[3] = w3;
#pragma unroll
        for (int dt = 0; dt < 2; ++dt)
          oacc[dt] = __builtin_amdgcn_mfma_f32_32x32x16_f16(vp[ks4 * 4 + kb2 * 2 + dt],
                                                            pf.v, oacc[dt], 0, 0, 0);
      }
      __builtin_amdgcn_s_setprio(0);
      // transpose readback (components already in k order) + coalesced nt
      // stores — after PV so LDS write latency hides under pack+MFMA
      float* srow = scores + (size_t)(bh * 2048 + q0 + w * 32) * 2048 + kb * 64 + ks4 * 32;
      {
        int qrd = l >> 3, k4 = l & 7, m4 = (l & 7) << 2;
#pragma unroll
        for (int j = 0; j < 4; ++j) {
          int q = qrd + 8 * j;
          int g = (k4 ^ (q >> 2)) & 7;
          f32x4 o = *(const f32x4*)(trw + q * 128 + (g << 4));
          __builtin_nontemporal_store(o, (f32x4*)(srow + (size_t)q * 2048 + m4));
        }
      }
    }
    __syncthreads();
  }
  // partial PV out (f16): opart[z][b*2048+qw][h*64+d]
  _Float16* orow = opart + (size_t)z * 4096 * 512 + (size_t)(b * 2048 + qw) * 512 + h * 64;
#pragma unroll
  for (int dt = 0; dt < 2; ++dt)
#pragma unroll
    for (int a = 0; a < 4; ++a) {
      int d = dt * 32 + 8 * a + 4 * hi;
      uint2 uu;
      uu.x = pkh(oacc[dt][4 * a + 0], oacc[dt][4 * a + 1]);
      uu.y = pkh(oacc[dt][4 * a + 2], oacc[dt][4 * a + 3]);
      *(uint2*)(orow + d) = uu;
    }
}

// ---------------------------------------------------------------------------
extern "C" void kernel_launch(void* const* d_in, const int* in_sizes, int n_in,
                              void* d_out, int out_size, void* d_ws, size_t ws_size,
                              hipStream_t stream) {
  const float* querys = (const float*)d_in[0];
  const float* keys   = (const float*)d_in[1];
  const float* values = (const float*)d_in[2];
  const float* mask   = (const float*)d_in[3];
  const float* Wq = (const float*)d_in[4];
  const float* Wk = (const float*)d_in[5];
  const float* Wv = (const float*)d_in[6];
  const float* Wo = (const float*)d_in[7];

  char* ws = (char*)d_ws;
  const size_t MB = 1048576;
  _Float16* q_r   = (_Float16*)(ws + 0 * MB);
  _Float16* k_r   = (_Float16*)(ws + 4 * MB);
  _Float16* v_t   = (_Float16*)(ws + 8 * MB);
  _Float16* opart = (_Float16*)(ws + 12 * MB);  // [4][4096][512] f16 = 16MB
  float*    lsums = (float*)(ws + 28 * MB);     // [4][16][2048] f32 = 512KB
  int*      flag  = (int*)(ws + 29 * MB);

  float* out_sc = (float*)d_out + (size_t)4096 * 512;

  (void)hipMemsetAsync(flag, 0, 4, stream);

  proj_kernel<<<dim3(4, 64, 4), 256, 0, stream>>>(querys, keys, values, Wq, Wk, Wv,
                                                  mask, flag, q_r, k_r, v_t);

  lsum_kernel<<<dim3(16, 16, 4), 256, 0, stream>>>(q_r, k_r, mask, flag, lsums);

  attn_kernel<<<dim3(16, 16, 4), 256, 0, stream>>>(q_r, k_r, v_t, mask, flag, lsums,
                                                   out_sc, opart);

  out_gemm<<<dim3(4, 64), 256, 0, stream>>>(opart, Wo, (float*)d_out);
}

// Round 19
// 176.977 us; speedup vs baseline: 1.0295x; 1.0295x over previous
//
#include <hip/hip_runtime.h>
#include <hip/hip_fp16.h>

typedef _Float16 f16x8 __attribute__((ext_vector_type(8)));
typedef _Float16 f16x4 __attribute__((ext_vector_type(4)));
typedef float f32x16 __attribute__((ext_vector_type(16)));
typedef float f32x4 __attribute__((ext_vector_type(4)));

#define LOG2E 1.44269504088896340736f
#define QSCALE 0.18033688011112042f      /* 0.125 * log2(e), folded into Q */
#define MASKC 1.8033688e8f               /* 1e9 * 0.125 * log2(e) */

typedef __attribute__((address_space(1))) const unsigned char gl_byte;
typedef __attribute__((address_space(3))) unsigned char lds_byte;

#define GLOAD_LDS16(g, l) \
  __builtin_amdgcn_global_load_lds((const gl_byte*)(g), (lds_byte*)(l), 16, 0, 0)

static __device__ __forceinline__ f32x16 zero16() {
  f32x16 z;
#pragma unroll
  for (int i = 0; i < 16; ++i) z[i] = 0.0f;
  return z;
}

static __device__ __forceinline__ unsigned pkh(float a, float b) {
  union { _Float16 h[2]; unsigned u; } t;
  t.h[0] = (_Float16)a; t.h[1] = (_Float16)b;
  return t.u;
}

// exchange: a = (hi ? partner's y : own x), c = (hi ? own y : partner's x)
static __device__ __forceinline__ void swap32(unsigned x, unsigned y, int hi,
                                              unsigned& a, unsigned& c) {
  unsigned py = (unsigned)__shfl_xor((int)y, 32);
  unsigned px = (unsigned)__shfl_xor((int)x, 32);
  a = hi ? py : x;
  c = hi ? y : px;
}

// XCD-aware bijective remap for 1024-block grids (16,16,4).
static __device__ __forceinline__ void xcd_remap_1k(int& q0, int& bh, int& z) {
  int lin = blockIdx.x + (blockIdx.y << 4) + (blockIdx.z << 8);
  int wid = ((lin & 7) << 7) | (lin >> 3);
  q0 = (wid & 15) * 128;
  bh = (wid >> 4) & 15;
  z = wid >> 8;
}

// 256-thread stage of one 64x64-half K tile (8KB): 2 DMA issues per thread
static __device__ __forceinline__ void stage_k64_256(char* dst,
                                                     const _Float16* __restrict__ kr,
                                                     int b, int h, int kb, int tid) {
#pragma unroll
  for (int it = 0; it < 2; ++it) {
    int s = it * 256 + tid;
    int r = s >> 3, c8 = (s & 7) ^ (r & 7);
    const _Float16* g = kr + (size_t)(b * 2048 + kb * 64 + r) * 512 + h * 64 + c8 * 8;
    GLOAD_LDS16(g, dst + (it * 256 + (tid & 192)) * 16);
  }
}

// ---------------------------------------------------------------------------
// Fused projections + mask scan.
// z=0 -> rope(q@Wq^T)*QSCALE, z=1 -> rope(k@Wk^T), z=2 -> v_t, z=3 -> mask.
// Tile 64(M) x 128(N), BK=64, 256 threads (4 waves, 2x2). grid (4, 64, 4).
// ---------------------------------------------------------------------------
__global__ __launch_bounds__(256) void proj_kernel(
    const float* __restrict__ qin, const float* __restrict__ kin,
    const float* __restrict__ vin, const float* __restrict__ Wq,
    const float* __restrict__ Wk, const float* __restrict__ Wv,
    const float* __restrict__ mask, int* __restrict__ flag,
    _Float16* __restrict__ q_r, _Float16* __restrict__ k_r,
    _Float16* __restrict__ v_t) {
  __shared__ char smem[8192 + 16384];  // As [64][64] f16, Ws [128][64] f16
  const int tid = threadIdx.x;
  const int zz = blockIdx.z;

  if (zz == 3) {  // mask scan: 256 blocks x 256 thr x 32 float4 = 64 MB
    int bid = blockIdx.y * 4 + blockIdx.x;
    const float4* m4p = (const float4*)mask;
    int base = bid * 8192 + tid;
    bool nz = false;
#pragma unroll 4
    for (int i = 0; i < 32; ++i) {
      float4 v = m4p[base + i * 256];
      nz |= (v.x != 0.f) || (v.y != 0.f) || (v.z != 0.f) || (v.w != 0.f);
    }
    if (__any(nz) && (tid & 63) == 0) atomicOr(flag, 1);
    return;
  }

  const int l = tid & 63, lo = l & 31, hi = l >> 5;
  const int w = tid >> 6, wm = w >> 1, wn = w & 1;
  const int m0 = blockIdx.y * 64, n0 = blockIdx.x * 128;
  const float* A = zz == 0 ? qin : zz == 1 ? kin : vin;
  const float* W = zz == 0 ? Wq : zz == 1 ? Wk : Wv;

  f32x16 acc[2];
  acc[0] = zero16();
  acc[1] = zero16();

  for (int kb = 0; kb < 8; ++kb) {
#pragma unroll
    for (int i = 0; i < 4; ++i) {
      int idx = tid + 256 * i; int r = idx >> 4, c4 = idx & 15;
      float4 v = *(const float4*)(A + (size_t)(m0 + r) * 512 + kb * 64 + c4 * 4);
      uint2 uu; uu.x = pkh(v.x, v.y); uu.y = pkh(v.z, v.w);
      *(uint2*)(smem + ((r * 128 + c4 * 8) ^ ((r & 7) << 4))) = uu;
    }
#pragma unroll
    for (int i = 0; i < 8; ++i) {
      int idx = tid + 256 * i; int r = idx >> 4, c4 = idx & 15;
      float4 v = *(const float4*)(W + (size_t)(n0 + r) * 512 + kb * 64 + c4 * 4);
      uint2 uu; uu.x = pkh(v.x, v.y); uu.y = pkh(v.z, v.w);
      *(uint2*)(smem + 8192 + ((r * 128 + c4 * 8) ^ ((r & 7) << 4))) = uu;
    }
    __syncthreads();
#pragma unroll
    for (int ks = 0; ks < 4; ++ks) {
      int ra = wm * 32 + lo;
      f16x8 a0 = *(const f16x8*)(smem + ((ra * 128 + ks * 32 + hi * 16) ^ ((ra & 7) << 4)));
      int rb0 = wn * 64 + lo, rb1 = rb0 + 32;
      f16x8 b0 = *(const f16x8*)(smem + 8192 + ((rb0 * 128 + ks * 32 + hi * 16) ^ ((rb0 & 7) << 4)));
      f16x8 b1 = *(const f16x8*)(smem + 8192 + ((rb1 * 128 + ks * 32 + hi * 16) ^ ((rb1 & 7) << 4)));
      acc[0] = __builtin_amdgcn_mfma_f32_32x32x16_f16(a0, b0, acc[0], 0, 0, 0);
      acc[1] = __builtin_amdgcn_mfma_f32_32x32x16_f16(a0, b1, acc[1], 0, 0, 0);
    }
    __syncthreads();
  }

  if (zz < 2) {
    _Float16* out = zz ? k_r : q_r;
#pragma unroll
    for (int nt = 0; nt < 2; ++nt) {
      int n = n0 + wn * 64 + nt * 32 + lo;
      int odd = lo & 1;
      int ii = (n >> 1) & 255;
      float fr = exp2f(-(float)ii * 0.05190512648261504f);
#pragma unroll
      for (int r = 0; r < 16; ++r) {
        int m = m0 + wm * 32 + (r & 3) + 8 * ((r >> 2) & 3) + 4 * hi;
        float a = acc[nt][r];
        float bb = __shfl_xor(a, 1);
        float xe = odd ? bb : a, xo = odd ? a : bb;
        float ang = (float)(m & 2047) * fr;
        float sn, cs;
        sincosf(ang, &sn, &cs);
        float res = odd ? (xo * cs + xe * sn) : (xe * cs - xo * sn);
        if (zz == 0) res *= QSCALE;  // fold softmax scale into Q
        out[(size_t)m * 512 + ii + (odd ? 256 : 0)] = (_Float16)res;
      }
    }
  } else {
#pragma unroll
    for (int nt = 0; nt < 2; ++nt) {
      int n = n0 + wn * 64 + nt * 32 + lo;
      int hh = n >> 6, d = n & 63;
#pragma unroll
      for (int a = 0; a < 4; ++a) {
        int m = m0 + wm * 32 + 8 * a + 4 * hi;
        int b_ = m >> 11, s = m & 2047;
        uint2 uu;
        uu.x = pkh(acc[nt][4 * a + 0], acc[nt][4 * a + 1]);
        uu.y = pkh(acc[nt][4 * a + 2], acc[nt][4 * a + 3]);
        *(uint2*)(v_t + (size_t)((b_ * 8 + hh) * 64 + d) * 2048 + s) = uu;
      }
    }
  }
}

// ---------------------------------------------------------------------------
// Output GEMM: d_out = (sum of 4 f16 PV partial slabs) @ Wo^T, f32 out.
// ---------------------------------------------------------------------------
__global__ __launch_bounds__(256) void out_gemm(const _Float16* __restrict__ opart,
                                                const float* __restrict__ W,
                                                float* __restrict__ out) {
  __shared__ char smem[8192 + 16384];
  const int tid = threadIdx.x;
  const int l = tid & 63, lo = l & 31, hi = l >> 5;
  const int w = tid >> 6, wm = w >> 1, wn = w & 1;
  const int m0 = blockIdx.y * 64, n0 = blockIdx.x * 128;
  const size_t slab = (size_t)4096 * 512;

  f32x16 acc[2];
  acc[0] = zero16();
  acc[1] = zero16();

  for (int kb = 0; kb < 8; ++kb) {
#pragma unroll
    for (int i = 0; i < 4; ++i) {
      int idx = tid + 256 * i; int r = idx >> 4, c4 = idx & 15;
      size_t off = (size_t)(m0 + r) * 512 + kb * 64 + c4 * 4;
      f16x4 x = *(const f16x4*)(opart + off);
      f16x4 y = *(const f16x4*)(opart + slab + off);
      f16x4 u = *(const f16x4*)(opart + 2 * slab + off);
      f16x4 t = *(const f16x4*)(opart + 3 * slab + off);
      float s0 = (float)x[0] + (float)y[0] + (float)u[0] + (float)t[0];
      float s1 = (float)x[1] + (float)y[1] + (float)u[1] + (float)t[1];
      float s2 = (float)x[2] + (float)y[2] + (float)u[2] + (float)t[2];
      float s3 = (float)x[3] + (float)y[3] + (float)u[3] + (float)t[3];
      uint2 uu; uu.x = pkh(s0, s1); uu.y = pkh(s2, s3);
      *(uint2*)(smem + ((r * 128 + c4 * 8) ^ ((r & 7) << 4))) = uu;
    }
#pragma unroll
    for (int i = 0; i < 8; ++i) {
      int idx = tid + 256 * i; int r = idx >> 4, c4 = idx & 15;
      float4 v = *(const float4*)(W + (size_t)(n0 + r) * 512 + kb * 64 + c4 * 4);
      uint2 uu; uu.x = pkh(v.x, v.y); uu.y = pkh(v.z, v.w);
      *(uint2*)(smem + 8192 + ((r * 128 + c4 * 8) ^ ((r & 7) << 4))) = uu;
    }
    __syncthreads();
#pragma unroll
    for (int ks = 0; ks < 4; ++ks) {
      int ra = wm * 32 + lo;
      f16x8 a0 = *(const f16x8*)(smem + ((ra * 128 + ks * 32 + hi * 16) ^ ((ra & 7) << 4)));
      int rb0 = wn * 64 + lo, rb1 = rb0 + 32;
      f16x8 b0 = *(const f16x8*)(smem + 8192 + ((rb0 * 128 + ks * 32 + hi * 16) ^ ((rb0 & 7) << 4)));
      f16x8 b1 = *(const f16x8*)(smem + 8192 + ((rb1 * 128 + ks * 32 + hi * 16) ^ ((rb1 & 7) << 4)));
      acc[0] = __builtin_amdgcn_mfma_f32_32x32x16_f16(a0, b0, acc[0], 0, 0, 0);
      acc[1] = __builtin_amdgcn_mfma_f32_32x32x16_f16(a0, b1, acc[1], 0, 0, 0);
    }
    __syncthreads();
  }

#pragma unroll
  for (int nt = 0; nt < 2; ++nt) {
    int n = n0 + wn * 64 + nt * 32 + lo;
#pragma unroll
    for (int r = 0; r < 16; ++r) {
      int m = m0 + wm * 32 + (r & 3) + 8 * ((r >> 2) & 3) + 4 * hi;
      out[(size_t)m * 512 + n] = acc[nt][r];
    }
  }
}

// ---------------------------------------------------------------------------
// Pass 1: softmax denominators, k-split 4.  grid (16 qt, 16 bh, 4 z), 256 thr
// (4 waves, q-tile 128).  LDS 16KB: K double-buffer 2x8KB.
// ---------------------------------------------------------------------------
__global__ __launch_bounds__(256, 4) void lsum_kernel(
    const _Float16* __restrict__ qr, const _Float16* __restrict__ kr,
    const float* __restrict__ mask, const int* __restrict__ flagp,
    float* __restrict__ lsums) {
  __shared__ char smem[16384];
  const int tid = threadIdx.x;
  const int w = tid >> 6, l = tid & 63, lo = l & 31, hi = l >> 5;
  int q0, bh, z;
  xcd_remap_1k(q0, bh, z);
  const int b = bh >> 3, h = bh & 7;
  const int mflag = *flagp;
  const int qw = q0 + w * 32 + lo;

  // Q B-fragments direct from global
  f16x8 qf[4];
  {
    const _Float16* qrow = qr + (size_t)(b * 2048 + qw) * 512 + h * 64 + hi * 8;
#pragma unroll
    for (int ks = 0; ks < 4; ++ks) qf[ks] = *(const f16x8*)(qrow + ks * 16);
  }

  const int kb0 = z * 8;
  stage_k64_256(smem, kr, b, h, kb0, tid);
  __syncthreads();

  float lsum = 0.f;
  for (int t = 0; t < 8; ++t) {
    const int cur = t & 1, kb = kb0 + t;
    if (t < 7) stage_k64_256(smem + (cur ^ 1) * 8192, kr, b, h, kb + 1, tid);
    char* kbuf = smem + cur * 8192;
#pragma unroll
    for (int ks4 = 0; ks4 < 2; ++ks4) {
      f32x16 acc = zero16();
      int krw = ks4 * 32 + lo;
#pragma unroll
      for (int ks = 0; ks < 4; ++ks) {
        f16x8 kf = *(const f16x8*)(kbuf + ((krw * 128 + ks * 32 + hi * 16) ^ ((krw & 7) << 4)));
        acc = __builtin_amdgcn_mfma_f32_32x32x16_f16(kf, qf[ks], acc, 0, 0, 0);
      }
      if (!mflag) {
#pragma unroll
        for (int r = 0; r < 16; ++r) lsum += exp2f(acc[r]);
      } else {
#pragma unroll
        for (int r = 0; r < 16; ++r) {
          int kg = kb * 64 + ks4 * 32 + (r & 3) + 8 * ((r >> 2) & 3) + 4 * hi;
          float mv = mask[(size_t)(b * 2048 + qw) * 2048 + kg];
          lsum += exp2f(acc[r] - MASKC * mv);
        }
      }
    }
    __syncthreads();
  }
  lsum += __shfl_xor(lsum, 32);
  if (hi == 0) lsums[(size_t)(z * 16 + bh) * 2048 + qw] = lsum;
}

// ---------------------------------------------------------------------------
// Pass 2: scores + partial PV, k-split 4.  grid (16 qt, 16 bh, 4 z), 256 thr
// (4 waves, q-tile 128): K staging + barrier amortized over 4 waves,
// block prologues halved, 16 waves/CU at VGPR<=128.
// LDS 32KB: K dbuf 2x8KB @0, per-wave f32 transpose @16384 (4KB/wave).
// ---------------------------------------------------------------------------
__global__ __launch_bounds__(256, 4) void attn_kernel(
    const _Float16* __restrict__ qr, const _Float16* __restrict__ kr,
    const _Float16* __restrict__ vt, const float* __restrict__ mask,
    const int* __restrict__ flagp, const float* __restrict__ lsums,
    float* __restrict__ scores, _Float16* __restrict__ opart) {
  __shared__ char smem[32768];
  const int tid = threadIdx.x;
  const int w = tid >> 6, l = tid & 63, lo = l & 31, hi = l >> 5;
  int q0, bh, z;
  xcd_remap_1k(q0, bh, z);
  const int b = bh >> 3, h = bh & 7;
  const int mflag = *flagp;
  const int qw = q0 + w * 32 + lo;

  f16x8 qf[4];
  {
    const _Float16* qrow = qr + (size_t)(b * 2048 + qw) * 512 + h * 64 + hi * 8;
#pragma unroll
    for (int ks = 0; ks < 4; ++ks) qf[ks] = *(const f16x8*)(qrow + ks * 16);
  }

  float lsum = 0.f;
#pragma unroll
  for (int zz = 0; zz < 4; ++zz) lsum += lsums[(size_t)(zz * 16 + bh) * 2048 + qw];
  const float linv = -log2f(lsum);  // fold 1/lsum into the exponent

  f32x16 oacc[2];
  oacc[0] = zero16();
  oacc[1] = zero16();
  char* trw = smem + 16384 + (w << 12);  // per-wave [32 q][8 groups x 16B]
  const _Float16* vbase = vt + (size_t)((b * 8 + h) * 64) * 2048;

  const int kb0 = z * 8;
  stage_k64_256(smem, kr, b, h, kb0, tid);
  __syncthreads();

  for (int t = 0; t < 8; ++t) {
    const int cur = t & 1, kb = kb0 + t;
    if (t < 7) stage_k64_256(smem + (cur ^ 1) * 8192, kr, b, h, kb + 1, tid);
    // prefetch V A-fragments for this tile (consumed after the S phase)
    f16x8 vp[8];
#pragma unroll
    for (int f = 0; f < 8; ++f) {
      int ks4 = f >> 2, kb2 = (f >> 1) & 1, dt = f & 1;
      int d = dt * 32 + lo;
      vp[f] = *(const f16x8*)(vbase + (size_t)d * 2048 + kb * 64 + ks4 * 32 + kb2 * 16 + hi * 8);
    }
    char* kbuf = smem + cur * 8192;
#pragma unroll
    for (int ks4 = 0; ks4 < 2; ++ks4) {
      f32x16 acc = zero16();
      int krw = ks4 * 32 + lo;
#pragma unroll
      for (int ks = 0; ks < 4; ++ks) {
        f16x8 kf = *(const f16x8*)(kbuf + ((krw * 128 + ks * 32 + hi * 16) ^ ((krw & 7) << 4)));
        acc = __builtin_amdgcn_mfma_f32_32x32x16_f16(kf, qf[ks], acc, 0, 0, 0);
      }
      float p[16];
      if (!mflag) {
#pragma unroll
        for (int r = 0; r < 16; ++r) p[r] = exp2f(acc[r] + linv);
      } else {
#pragma unroll
        for (int r = 0; r < 16; ++r) {
          int kg = kb * 64 + ks4 * 32 + (r & 3) + 8 * ((r >> 2) & 3) + 4 * hi;
          float mv = mask[(size_t)(b * 2048 + qw) * 2048 + kg];
          p[r] = exp2f(acc[r] - MASKC * mv + linv);
        }
      }
      // quad transpose writes: p[4a..4a+3] -> group (2a+hi)^(lo>>2) of row lo
#pragma unroll
      for (int a = 0; a < 4; ++a) {
        int g = ((2 * a + hi) ^ (lo >> 2)) & 7;
        f32x4 v;
        v[0] = p[4 * a + 0]; v[1] = p[4 * a + 1];
        v[2] = p[4 * a + 2]; v[3] = p[4 * a + 3];
        *(f32x4*)(trw + lo * 128 + (g << 4)) = v;
      }
      // PV: build P^T fragments in-register, A = prefetched V fragments
#pragma unroll
      for (int kb2 = 0; kb2 < 2; ++kb2) {
        unsigned X0 = pkh(p[8 * kb2 + 0], p[8 * kb2 + 1]);
        unsigned X1 = pkh(p[8 * kb2 + 2], p[8 * kb2 + 3]);
        unsigned Y0 = pkh(p[8 * kb2 + 4], p[8 * kb2 + 5]);
        unsigned Y1 = pkh(p[8 * kb2 + 6], p[8 * kb2 + 7]);
        unsigned w0, w1, w2, w3;
        swap32(X0, Y0, hi, w0, w2);
        swap32(X1, Y1, hi, w1, w3);
        union { unsigned u[4]; f16x8 v; } pf;
        pf.u[0] = w0; pf.u[1] = w1; pf.u[2] = w2; pf.u[3] = w3;
#pragma unroll
        for (int dt = 0; dt < 2; ++dt)
          oacc[dt] = __builtin_amdgcn_mfma_f32_32x32x16_f16(vp[ks4 * 4 + kb2 * 2 + dt],
                                                            pf.v, oacc[dt], 0, 0, 0);
      }
      // transpose readback (components already in k order) + coalesced nt
      // stores — after PV so LDS write latency hides under pack+MFMA
      float* srow = scores + (size_t)(bh * 2048 + q0 + w * 32) * 2048 + kb * 64 + ks4 * 32;
      {
        int qrd = l >> 3, k4 = l & 7, m4 = (l & 7) << 2;
#pragma unroll
        for (int j = 0; j < 4; ++j) {
          int q = qrd + 8 * j;
          int g = (k4 ^ (q >> 2)) & 7;
          f32x4 o = *(const f32x4*)(trw + q * 128 + (g << 4));
          __builtin_nontemporal_store(o, (f32x4*)(srow + (size_t)q * 2048 + m4));
        }
      }
    }
    __syncthreads();
  }
  // partial PV out (f16): opart[z][b*2048+qw][h*64+d]
  _Float16* orow = opart + (size_t)z * 4096 * 512 + (size_t)(b * 2048 + qw) * 512 + h * 64;
#pragma unroll
  for (int dt = 0; dt < 2; ++dt)
#pragma unroll
    for (int a = 0; a < 4; ++a) {
      int d = dt * 32 + 8 * a + 4 * hi;
      uint2 uu;
      uu.x = pkh(oacc[dt][4 * a + 0], oacc[dt][4 * a + 1]);
      uu.y = pkh(oacc[dt][4 * a + 2], oacc[dt][4 * a + 3]);
      *(uint2*)(orow + d) = uu;
    }
}

// ---------------------------------------------------------------------------
extern "C" void kernel_launch(void* const* d_in, const int* in_sizes, int n_in,
                              void* d_out, int out_size, void* d_ws, size_t ws_size,
                              hipStream_t stream) {
  const float* querys = (const float*)d_in[0];
  const float* keys   = (const float*)d_in[1];
  const float* values = (const float*)d_in[2];
  const float* mask   = (const float*)d_in[3];
  const float* Wq = (const float*)d_in[4];
  const float* Wk = (const float*)d_in[5];
  const float* Wv = (const float*)d_in[6];
  const float* Wo = (const float*)d_in[7];

  char* ws = (char*)d_ws;
  const size_t MB = 1048576;
  _Float16* q_r   = (_Float16*)(ws + 0 * MB);
  _Float16* k_r   = (_Float16*)(ws + 4 * MB);
  _Float16* v_t   = (_Float16*)(ws + 8 * MB);
  _Float16* opart = (_Float16*)(ws + 12 * MB);  // [4][4096][512] f16 = 16MB
  float*    lsums = (float*)(ws + 28 * MB);     // [4][16][2048] f32 = 512KB
  int*      flag  = (int*)(ws + 29 * MB);

  float* out_sc = (float*)d_out + (size_t)4096 * 512;

  (void)hipMemsetAsync(flag, 0, 4, stream);

  proj_kernel<<<dim3(4, 64, 4), 256, 0, stream>>>(querys, keys, values, Wq, Wk, Wv,
                                                  mask, flag, q_r, k_r, v_t);

  lsum_kernel<<<dim3(16, 16, 4), 256, 0, stream>>>(q_r, k_r, mask, flag, lsums);

  attn_kernel<<<dim3(16, 16, 4), 256, 0, stream>>>(q_r, k_r, v_t, mask, flag, lsums,
                                                   out_sc, opart);

  out_gemm<<<dim3(4, 64), 256, 0, stream>>>(opart, Wo, (float*)d_out);
}